// Round 3
// baseline (7335.223 us; speedup 1.0000x reference)
//
#include <hip/hip_runtime.h>
#include <math.h>

// Restarted GMRES(16), 4 cycles, Helmholtz (-lap + 0.3) on 1024x1024 periodic fp32.
// Round 3: single persistent kernel, custom grid barrier, full Krylov basis cached
// in registers (vc[16] per thread, 4 elems each). Global traffic = stencil reads +
// wstag writes only (~0.9 GB total vs 8.4 GB in round 2).

#define NGRID 1024
#define NE (NGRID*NGRID)
#define NB 512            // blocks
#define TPB 512           // threads per block (8 waves)
#define RST 16
#define KMAX 17
#define NCYC 4

__device__ __forceinline__ float4 ld4(const float* p){return *reinterpret_cast<const float4*>(p);}
__device__ __forceinline__ void st4(float* p, float4 v){*reinterpret_cast<float4*>(p)=v;}
__device__ __forceinline__ float dot4(float4 a,float4 b){return a.x*b.x+a.y*b.y+a.z*b.z+a.w*b.w;}

__device__ __forceinline__ float wave_reduce(float s){
  #pragma unroll
  for(int off=32; off; off>>=1) s += __shfl_down(s,off);
  return s;
}

// reduce one column of NB=512 floats with a single wave (8 per lane)
__device__ __forceinline__ float col_reduce512(const float* col, int lane){
  float4 p0 = ld4(col + lane*8);
  float4 p1 = ld4(col + lane*8 + 4);
  float s = ((p0.x+p0.y)+(p0.z+p0.w)) + ((p1.x+p1.y)+(p1.z+p1.w));
  return wave_reduce(s);
}

// sense-reversing grid barrier; agent-scope acquire/release atomics carry the
// cross-XCD visibility (L2 writeback on release, invalidate on acquire).
__device__ __forceinline__ void gridbar(int* cnt, int* gen){
  __syncthreads();
  if(threadIdx.x==0){
    int g = __hip_atomic_load(gen, __ATOMIC_RELAXED, __HIP_MEMORY_SCOPE_AGENT);
    int a = __hip_atomic_fetch_add(cnt, 1, __ATOMIC_ACQ_REL, __HIP_MEMORY_SCOPE_AGENT);
    if(a == NB-1){
      __hip_atomic_store(cnt, 0, __ATOMIC_RELAXED, __HIP_MEMORY_SCOPE_AGENT);
      __hip_atomic_fetch_add(gen, 1, __ATOMIC_RELEASE, __HIP_MEMORY_SCOPE_AGENT);
    } else {
      while(__hip_atomic_load(gen, __ATOMIC_ACQUIRE, __HIP_MEMORY_SCOPE_AGENT)==g)
        __builtin_amdgcn_s_sleep(1);
    }
  }
  __syncthreads();
}

// A(u*inv) at this thread's 4 elements; center c is already scaled (= u*inv here).
__device__ __forceinline__ float4 stencil_scaled(const float* __restrict__ u, float inv,
                                                 float4 c, int upo, int dno,
                                                 int lfi, int rti, int jc){
  float4 a = ld4(u + upo + jc);
  float4 d = ld4(u + dno + jc);
  float lf = u[lfi]*inv, rt = u[rti]*inv;
  a.x*=inv; a.y*=inv; a.z*=inv; a.w*=inv;
  d.x*=inv; d.y*=inv; d.z*=inv; d.w*=inv;
  float4 o;
  o.x = 0.3f*c.x - ((a.x + d.x + lf  + c.y) - 4.0f*c.x);
  o.y = 0.3f*c.y - ((a.y + d.y + c.x + c.z) - 4.0f*c.y);
  o.z = 0.3f*c.z - ((a.z + d.z + c.y + c.w) - 4.0f*c.z);
  o.w = 0.3f*c.w - ((a.w + d.w + c.z + rt ) - 4.0f*c.w);
  return o;
}

__global__ __launch_bounds__(TPB, 4) void k_gmres(
    const float* __restrict__ b, const float* __restrict__ guess,
    float* __restrict__ x, float* __restrict__ wstag,
    float* __restrict__ pdA, float* __restrict__ pdB, float* __restrict__ pn,
    int* __restrict__ cnt, int* __restrict__ gen)
{
  const int t = threadIdx.x, blk = blockIdx.x;
  const int elem = blk*(TPB*4) + t*4;
  const int i = elem >> 10, jc = elem & (NGRID-1);
  const int upo = ((i + NGRID-1) & (NGRID-1)) << 10;
  const int dno = ((i + 1) & (NGRID-1)) << 10;
  const int lfi = (i<<10) | ((jc + NGRID-1) & (NGRID-1));
  const int rti = (i<<10) | ((jc + 4) & (NGRID-1));
  const int lane = t & 63, wv = t >> 6;

  __shared__ float red[KMAX][8];
  __shared__ float sH[KMAX], hsave[KMAX];
  __shared__ float Hm[KMAX][RST];
  __shared__ float M[RST][RST+1];
  __shared__ float yv[RST];
  __shared__ float snrm, sBeta;

  float4 x4 = ld4(guess + elem);
  float4 w4;
  float4 vc[RST];

  #pragma unroll 1
  for (int cyc = 0; cyc < NCYC; ++cyc) {
    // zero Hm (first use is after at least one gridbar)
    for (int q = t; q < KMAX*RST; q += TPB) ((float*)Hm)[q] = 0.0f;

    // ---- RESID: w = b - A(x); norm partial ----
    const float* xs = (cyc == 0) ? guess : x;
    float4 ax = stencil_scaled(xs, 1.0f, x4, upo, dno, lfi, rti, jc);
    float4 b4 = ld4(b + elem);
    w4.x = b4.x - ax.x; w4.y = b4.y - ax.y; w4.z = b4.z - ax.z; w4.w = b4.w - ax.w;
    st4(wstag + elem, w4);
    {
      float s = wave_reduce(dot4(w4, w4));
      if (lane == 0) red[16][wv] = s;
      __syncthreads();
      if (t == 0) {
        float acc = 0.f;
        #pragma unroll
        for (int q = 0; q < 8; ++q) acc += red[16][q];
        pn[blk] = acc;
      }
    }
    gridbar(cnt, gen);

    #pragma unroll
    for (int J = 0; J < RST; ++J) {
      // ---- PHASE 1: norm -> inv; vc[J] = w*inv; aw = A(wstag*inv); first dots ----
      {
        if (wv == 0) { float s = col_reduce512(pn, lane); if (lane == 0) snrm = s; }
        __syncthreads();
        float hn = sqrtf(snrm);
        float inv = 1.0f/(hn + 1e-12f);
        if (t == 0) { if (J == 0) sBeta = hn; else Hm[J][J-1] = hn; }
        vc[J].x = w4.x*inv; vc[J].y = w4.y*inv; vc[J].z = w4.z*inv; vc[J].w = w4.w*inv;
        w4 = stencil_scaled(wstag, inv, vc[J], upo, dno, lfi, rti, jc);
        #pragma unroll
        for (int k = 0; k <= J; ++k) {
          float s = wave_reduce(dot4(vc[k], w4));
          if (lane == 0) red[k][wv] = s;
        }
        __syncthreads();
        if (t <= J) {
          float acc = 0.f;
          #pragma unroll
          for (int q = 0; q < 8; ++q) acc += red[t][q];
          pdA[t*NB + blk] = acc;
        }
      }
      gridbar(cnt, gen);
      // ---- PHASE 2: reduce h; axpy1; second dots ----
      {
        for (int k = wv; k <= J; k += 8) {
          float s = col_reduce512(pdA + k*NB, lane);
          if (lane == 0) sH[k] = s;
        }
        __syncthreads();
        #pragma unroll
        for (int k = 0; k <= J; ++k) {
          float hk = sH[k];
          w4.x -= hk*vc[k].x; w4.y -= hk*vc[k].y; w4.z -= hk*vc[k].z; w4.w -= hk*vc[k].w;
        }
        if (t <= J) hsave[t] = sH[t];
        #pragma unroll
        for (int k = 0; k <= J; ++k) {
          float s = wave_reduce(dot4(vc[k], w4));
          if (lane == 0) red[k][wv] = s;
        }
        __syncthreads();
        if (t <= J) {
          float acc = 0.f;
          #pragma unroll
          for (int q = 0; q < 8; ++q) acc += red[t][q];
          pdB[t*NB + blk] = acc;
        }
      }
      gridbar(cnt, gen);
      // ---- PHASE 3: reduce h2; axpy2; Hm column; norm partial; stage w ----
      {
        for (int k = wv; k <= J; k += 8) {
          float s = col_reduce512(pdB + k*NB, lane);
          if (lane == 0) sH[k] = s;
        }
        __syncthreads();
        #pragma unroll
        for (int k = 0; k <= J; ++k) {
          float hk = sH[k];
          w4.x -= hk*vc[k].x; w4.y -= hk*vc[k].y; w4.z -= hk*vc[k].z; w4.w -= hk*vc[k].w;
        }
        if (t <= J) Hm[t][J] = hsave[t] + sH[t];
        float s = wave_reduce(dot4(w4, w4));
        if (lane == 0) red[16][wv] = s;
        __syncthreads();
        if (t == 0) {
          float acc = 0.f;
          #pragma unroll
          for (int q = 0; q < 8; ++q) acc += red[16][q];
          pn[blk] = acc;
        }
        if (J < RST-1) st4(wstag + elem, w4);
      }
      gridbar(cnt, gen);
    }

    // ---- EPILOGUE: Hm[16][15]; solve 16x16 normal equations; x += V y ----
    {
      if (wv == 0) { float s = col_reduce512(pn, lane); if (lane == 0) snrm = s; }
      __syncthreads();
      if (t == 0) Hm[16][15] = sqrtf(snrm);
      __syncthreads();
      if (t < 256) {
        int a = t >> 4, bq = t & 15;
        float s = 0.f;
        #pragma unroll
        for (int k = 0; k < KMAX; ++k) s += Hm[k][a]*Hm[k][bq];
        M[a][bq] = s + (a == bq ? 1e-12f : 0.0f);
      }
      __syncthreads();
      if (t < RST) M[t][RST] = sBeta * Hm[0][t];
      __syncthreads();
      for (int c = 0; c < RST; ++c) {
        if (t == 0) {
          int p = c; float mx = fabsf(M[c][c]);
          for (int r = c+1; r < RST; ++r){ float v=fabsf(M[r][c]); if (v>mx){mx=v;p=r;} }
          if (p != c) for (int cc = c; cc <= RST; ++cc){ float tmp=M[c][cc]; M[c][cc]=M[p][cc]; M[p][cc]=tmp; }
        }
        __syncthreads();
        if (t > c && t < RST) {
          float f = M[t][c]/M[c][c];
          for (int cc = c; cc <= RST; ++cc) M[t][cc] -= f*M[c][cc];
        }
        __syncthreads();
      }
      if (t == 0) {
        for (int c = RST-1; c >= 0; --c) {
          float s = M[c][RST];
          for (int cc = c+1; cc < RST; ++cc) s -= M[c][cc]*yv[cc];
          yv[c] = s/M[c][c];
        }
      }
      __syncthreads();
      #pragma unroll
      for (int k = 0; k < RST; ++k) {
        float yk = yv[k];
        x4.x += yk*vc[k].x; x4.y += yk*vc[k].y; x4.z += yk*vc[k].z; x4.w += yk*vc[k].w;
      }
      st4(x + elem, x4);
    }
    gridbar(cnt, gen);   // x visible for next cycle's residual stencil
  }
}

extern "C" void kernel_launch(void* const* d_in, const int* in_sizes, int n_in,
                              void* d_out, int out_size, void* d_ws, size_t ws_size,
                              hipStream_t stream) {
  const float* b     = (const float*)d_in[0];   // source
  const float* guess = (const float*)d_in[1];   // initial guess
  float* x  = (float*)d_out;
  float* ws = (float*)d_ws;

  float* wstag = ws;                       // NE
  float* pdA   = ws + NE;                  // KMAX*NB
  float* pdB   = pdA + KMAX*NB;            // KMAX*NB
  float* pn    = pdB + KMAX*NB;            // NB
  int*   bar   = (int*)(pn + NB);          // barrier counters

  hipMemsetAsync(bar, 0, 512, stream);     // cnt at bar[0], gen at bar[64]

  k_gmres<<<NB, TPB, 0, stream>>>(b, guess, x, wstag, pdA, pdB, pn,
                                  bar, bar + 64);
}

// Round 4
// 4597.792 us; speedup vs baseline: 1.5954x; 1.5954x over previous
//
#include <hip/hip_runtime.h>
#include <math.h>

// Restarted GMRES(16), 4 cycles, Helmholtz (-lap + 0.3) on 1024x1024 periodic fp32.
// Round 4: persistent kernel with register-resident Krylov basis (vc[16] per thread)
// + RMW-free flag-tree grid barrier (round 3's single-counter fetch_add serialized
// 512 blocks x 200 barriers ~= 7 ms; this replaces it with one release-store per
// block + block-0 poll + broadcast gen, relaxed polls, single acquire at exit).

#define NGRID 1024
#define NE (NGRID*NGRID)
#define NB 512            // blocks
#define TPB 512           // threads per block (8 waves)
#define RST 16
#define KMAX 17
#define NCYC 4
#define FLAG_STRIDE 16    // pad arrive flags to 64B

__device__ __forceinline__ float4 ld4(const float* p){return *reinterpret_cast<const float4*>(p);}
__device__ __forceinline__ void st4(float* p, float4 v){*reinterpret_cast<float4*>(p)=v;}
__device__ __forceinline__ float dot4(float4 a,float4 b){return a.x*b.x+a.y*b.y+a.z*b.z+a.w*b.w;}

__device__ __forceinline__ float wave_reduce(float s){
  #pragma unroll
  for(int off=32; off; off>>=1) s += __shfl_down(s,off);
  return s;
}

// reduce one column of NB=512 floats with a single wave (8 per lane)
__device__ __forceinline__ float col_reduce512(const float* col, int lane){
  float4 p0 = ld4(col + lane*8);
  float4 p1 = ld4(col + lane*8 + 4);
  float s = ((p0.x+p0.y)+(p0.z+p0.w)) + ((p1.x+p1.y)+(p1.z+p1.w));
  return wave_reduce(s);
}

// RMW-free grid barrier. bar_id strictly increases; flags start at 0.
__device__ __forceinline__ void gridbar(int* arrive, int* gen, int bar_id,
                                        int blk, int t){
  __syncthreads();
  if (t == 0)
    __hip_atomic_store(&arrive[blk*FLAG_STRIDE], bar_id,
                       __ATOMIC_RELEASE, __HIP_MEMORY_SCOPE_AGENT);
  if (blk == 0) {
    while (__hip_atomic_load(&arrive[t*FLAG_STRIDE],
                             __ATOMIC_RELAXED, __HIP_MEMORY_SCOPE_AGENT) < bar_id)
      __builtin_amdgcn_s_sleep(1);
    __syncthreads();
    if (t == 0)
      __hip_atomic_store(gen, bar_id, __ATOMIC_RELEASE, __HIP_MEMORY_SCOPE_AGENT);
  }
  if (t == 0) {
    while (__hip_atomic_load(gen, __ATOMIC_RELAXED, __HIP_MEMORY_SCOPE_AGENT) < bar_id)
      __builtin_amdgcn_s_sleep(1);
    (void)__hip_atomic_load(gen, __ATOMIC_ACQUIRE, __HIP_MEMORY_SCOPE_AGENT);
  }
  __syncthreads();
}

// A(u*inv) at this thread's 4 elements; center c is already scaled (= u*inv).
__device__ __forceinline__ float4 stencil_scaled(const float* __restrict__ u, float inv,
                                                 float4 c, int upo, int dno,
                                                 int lfi, int rti, int jc){
  float4 a = ld4(u + upo + jc);
  float4 d = ld4(u + dno + jc);
  float lf = u[lfi]*inv, rt = u[rti]*inv;
  a.x*=inv; a.y*=inv; a.z*=inv; a.w*=inv;
  d.x*=inv; d.y*=inv; d.z*=inv; d.w*=inv;
  float4 o;
  o.x = 0.3f*c.x - ((a.x + d.x + lf  + c.y) - 4.0f*c.x);
  o.y = 0.3f*c.y - ((a.y + d.y + c.x + c.z) - 4.0f*c.y);
  o.z = 0.3f*c.z - ((a.z + d.z + c.y + c.w) - 4.0f*c.z);
  o.w = 0.3f*c.w - ((a.w + d.w + c.z + rt ) - 4.0f*c.w);
  return o;
}

__global__ __launch_bounds__(TPB, 4) void k_gmres(
    const float* __restrict__ b, const float* __restrict__ guess,
    float* __restrict__ x, float* __restrict__ wstag,
    float* __restrict__ pdA, float* __restrict__ pdB, float* __restrict__ pn,
    int* __restrict__ arrive, int* __restrict__ gen)
{
  const int t = threadIdx.x, blk = blockIdx.x;
  const int elem = blk*(TPB*4) + t*4;
  const int i = elem >> 10, jc = elem & (NGRID-1);
  const int upo = ((i + NGRID-1) & (NGRID-1)) << 10;
  const int dno = ((i + 1) & (NGRID-1)) << 10;
  const int lfi = (i<<10) | ((jc + NGRID-1) & (NGRID-1));
  const int rti = (i<<10) | ((jc + 4) & (NGRID-1));
  const int lane = t & 63, wv = t >> 6;

  __shared__ float red[KMAX][8];
  __shared__ float sH[KMAX], hsave[KMAX];
  __shared__ float Hm[KMAX][RST];
  __shared__ float M[RST][RST+1];
  __shared__ float yv[RST];
  __shared__ float snrm, sBeta;

  float4 x4 = ld4(guess + elem);
  float4 w4;
  float4 vc[RST];
  int bid = 1;   // monotonically increasing barrier id

  #pragma unroll 1
  for (int cyc = 0; cyc < NCYC; ++cyc) {
    for (int q = t; q < KMAX*RST; q += TPB) ((float*)Hm)[q] = 0.0f;

    // ---- RESID: w = b - A(x); norm partial ----
    const float* xs = (cyc == 0) ? guess : x;
    float4 ax = stencil_scaled(xs, 1.0f, x4, upo, dno, lfi, rti, jc);
    float4 b4 = ld4(b + elem);
    w4.x = b4.x - ax.x; w4.y = b4.y - ax.y; w4.z = b4.z - ax.z; w4.w = b4.w - ax.w;
    st4(wstag + elem, w4);
    {
      float s = wave_reduce(dot4(w4, w4));
      if (lane == 0) red[16][wv] = s;
      __syncthreads();
      if (t == 0) {
        float acc = 0.f;
        #pragma unroll
        for (int q = 0; q < 8; ++q) acc += red[16][q];
        pn[blk] = acc;
      }
    }
    gridbar(arrive, gen, bid++, blk, t);

    #pragma unroll
    for (int J = 0; J < RST; ++J) {
      // ---- PHASE 1: norm -> inv; vc[J] = w*inv; w = A(wstag*inv); first dots ----
      {
        if (wv == 0) { float s = col_reduce512(pn, lane); if (lane == 0) snrm = s; }
        __syncthreads();
        float hn = sqrtf(snrm);
        float inv = 1.0f/(hn + 1e-12f);
        if (t == 0) { if (J == 0) sBeta = hn; else Hm[J][J-1] = hn; }
        vc[J].x = w4.x*inv; vc[J].y = w4.y*inv; vc[J].z = w4.z*inv; vc[J].w = w4.w*inv;
        w4 = stencil_scaled(wstag, inv, vc[J], upo, dno, lfi, rti, jc);
        #pragma unroll
        for (int k = 0; k <= J; ++k) {
          float s = wave_reduce(dot4(vc[k], w4));
          if (lane == 0) red[k][wv] = s;
        }
        __syncthreads();
        if (t <= J) {
          float acc = 0.f;
          #pragma unroll
          for (int q = 0; q < 8; ++q) acc += red[t][q];
          pdA[t*NB + blk] = acc;
        }
      }
      gridbar(arrive, gen, bid++, blk, t);
      // ---- PHASE 2: reduce h; axpy1; second dots ----
      {
        for (int k = wv; k <= J; k += 8) {
          float s = col_reduce512(pdA + k*NB, lane);
          if (lane == 0) sH[k] = s;
        }
        __syncthreads();
        #pragma unroll
        for (int k = 0; k <= J; ++k) {
          float hk = sH[k];
          w4.x -= hk*vc[k].x; w4.y -= hk*vc[k].y; w4.z -= hk*vc[k].z; w4.w -= hk*vc[k].w;
        }
        if (t <= J) hsave[t] = sH[t];
        #pragma unroll
        for (int k = 0; k <= J; ++k) {
          float s = wave_reduce(dot4(vc[k], w4));
          if (lane == 0) red[k][wv] = s;
        }
        __syncthreads();
        if (t <= J) {
          float acc = 0.f;
          #pragma unroll
          for (int q = 0; q < 8; ++q) acc += red[t][q];
          pdB[t*NB + blk] = acc;
        }
      }
      gridbar(arrive, gen, bid++, blk, t);
      // ---- PHASE 3: reduce h2; axpy2; Hm column; norm partial; stage w ----
      {
        for (int k = wv; k <= J; k += 8) {
          float s = col_reduce512(pdB + k*NB, lane);
          if (lane == 0) sH[k] = s;
        }
        __syncthreads();
        #pragma unroll
        for (int k = 0; k <= J; ++k) {
          float hk = sH[k];
          w4.x -= hk*vc[k].x; w4.y -= hk*vc[k].y; w4.z -= hk*vc[k].z; w4.w -= hk*vc[k].w;
        }
        if (t <= J) Hm[t][J] = hsave[t] + sH[t];
        float s = wave_reduce(dot4(w4, w4));
        if (lane == 0) red[16][wv] = s;
        __syncthreads();
        if (t == 0) {
          float acc = 0.f;
          #pragma unroll
          for (int q = 0; q < 8; ++q) acc += red[16][q];
          pn[blk] = acc;
        }
        if (J < RST-1) st4(wstag + elem, w4);
      }
      gridbar(arrive, gen, bid++, blk, t);
    }

    // ---- EPILOGUE: Hm[16][15]; solve 16x16 normal equations; x += V y ----
    {
      if (wv == 0) { float s = col_reduce512(pn, lane); if (lane == 0) snrm = s; }
      __syncthreads();
      if (t == 0) Hm[16][15] = sqrtf(snrm);
      __syncthreads();
      if (t < 256) {
        int a = t >> 4, bq = t & 15;
        float s = 0.f;
        #pragma unroll
        for (int k = 0; k < KMAX; ++k) s += Hm[k][a]*Hm[k][bq];
        M[a][bq] = s + (a == bq ? 1e-12f : 0.0f);
      }
      __syncthreads();
      if (t < RST) M[t][RST] = sBeta * Hm[0][t];
      __syncthreads();
      for (int c = 0; c < RST; ++c) {
        if (t == 0) {
          int p = c; float mx = fabsf(M[c][c]);
          for (int r = c+1; r < RST; ++r){ float v=fabsf(M[r][c]); if (v>mx){mx=v;p=r;} }
          if (p != c) for (int cc = c; cc <= RST; ++cc){ float tmp=M[c][cc]; M[c][cc]=M[p][cc]; M[p][cc]=tmp; }
        }
        __syncthreads();
        if (t > c && t < RST) {
          float f = M[t][c]/M[c][c];
          for (int cc = c; cc <= RST; ++cc) M[t][cc] -= f*M[c][cc];
        }
        __syncthreads();
      }
      if (t == 0) {
        for (int c = RST-1; c >= 0; --c) {
          float s = M[c][RST];
          for (int cc = c+1; cc < RST; ++cc) s -= M[c][cc]*yv[cc];
          yv[c] = s/M[c][c];
        }
      }
      __syncthreads();
      #pragma unroll
      for (int k = 0; k < RST; ++k) {
        float yk = yv[k];
        x4.x += yk*vc[k].x; x4.y += yk*vc[k].y; x4.z += yk*vc[k].z; x4.w += yk*vc[k].w;
      }
      st4(x + elem, x4);
    }
    if (cyc < NCYC-1)
      gridbar(arrive, gen, bid++, blk, t);   // x visible for next cycle's residual
  }
}

extern "C" void kernel_launch(void* const* d_in, const int* in_sizes, int n_in,
                              void* d_out, int out_size, void* d_ws, size_t ws_size,
                              hipStream_t stream) {
  const float* b     = (const float*)d_in[0];   // source
  const float* guess = (const float*)d_in[1];   // initial guess
  float* x  = (float*)d_out;
  float* ws = (float*)d_ws;

  float* wstag = ws;                       // NE
  float* pdA   = ws + NE;                  // KMAX*NB
  float* pdB   = pdA + KMAX*NB;            // KMAX*NB
  float* pn    = pdB + KMAX*NB;            // NB
  int*   barm  = (int*)(pn + NB);          // arrive[NB*16] + gen

  hipMemsetAsync(barm, 0, (NB*FLAG_STRIDE + 64)*sizeof(int), stream);

  k_gmres<<<NB, TPB, 0, stream>>>(b, guess, x, wstag, pdA, pdB, pn,
                                  barm, barm + NB*FLAG_STRIDE);
}

// Round 5
// 3085.658 us; speedup vs baseline: 2.3772x; 1.4901x over previous
//
#include <hip/hip_runtime.h>
#include <math.h>

// Restarted GMRES(16), 4 cycles, Helmholtz (-lap + 0.3) on 1024x1024 periodic fp32.
// Round 5: persistent kernel, register-resident Krylov basis (vc[16] per thread,
// 4 elems), all-to-all single-hop grid barrier (each block polls every arrive flag
// directly; no central gen line), NB=256 x TPB=1024 to halve barrier fan-in and
// the O(NB^2) redundant partial-column reads.

#define NGRID 1024
#define NE (NGRID*NGRID)
#define NB 256            // blocks (= CUs)
#define TPB 1024          // threads per block (16 waves)
#define RST 16
#define KMAX 17
#define NCYC 4
#define FLAG_STRIDE 16    // pad arrive flags to 64B

__device__ __forceinline__ float4 ld4(const float* p){return *reinterpret_cast<const float4*>(p);}
__device__ __forceinline__ void st4(float* p, float4 v){*reinterpret_cast<float4*>(p)=v;}
__device__ __forceinline__ float dot4(float4 a,float4 b){return a.x*b.x+a.y*b.y+a.z*b.z+a.w*b.w;}

__device__ __forceinline__ float wave_reduce(float s){
  #pragma unroll
  for(int off=32; off; off>>=1) s += __shfl_down(s,off);
  return s;
}

// reduce one column of NB=256 floats with a single wave (float4 per lane)
__device__ __forceinline__ float col_reduce256(const float* col, int lane){
  float4 p0 = ld4(col + lane*4);
  float s = (p0.x+p0.y)+(p0.z+p0.w);
  return wave_reduce(s);
}

// all-to-all grid barrier: one release-store per block, every block polls all
// NB flags (one per thread, relaxed), then a single wave-0 acquire fence
// (buffer_inv: CU L1 + XCD L2). bar_id strictly increases; flags start at 0.
__device__ __forceinline__ void gridbar(int* arrive, int bar_id, int blk, int t, int wv){
  __syncthreads();   // all waves' stores drained to L2 (vmcnt(0) before s_barrier)
  if (t == 0)
    __hip_atomic_store(&arrive[blk*FLAG_STRIDE], bar_id,
                       __ATOMIC_RELEASE, __HIP_MEMORY_SCOPE_AGENT);
  if (t < NB) {
    while (__hip_atomic_load(&arrive[t*FLAG_STRIDE],
                             __ATOMIC_RELAXED, __HIP_MEMORY_SCOPE_AGENT) < bar_id)
      __builtin_amdgcn_s_sleep(1);
  }
  __syncthreads();
  if (wv == 0) __builtin_amdgcn_fence(__ATOMIC_ACQUIRE, "agent");
  __syncthreads();
}

// A(u*inv) at this thread's 4 elements; center c is already scaled (= u*inv).
__device__ __forceinline__ float4 stencil_scaled(const float* __restrict__ u, float inv,
                                                 float4 c, int upo, int dno,
                                                 int lfi, int rti, int jc){
  float4 a = ld4(u + upo + jc);
  float4 d = ld4(u + dno + jc);
  float lf = u[lfi]*inv, rt = u[rti]*inv;
  a.x*=inv; a.y*=inv; a.z*=inv; a.w*=inv;
  d.x*=inv; d.y*=inv; d.z*=inv; d.w*=inv;
  float4 o;
  o.x = 0.3f*c.x - ((a.x + d.x + lf  + c.y) - 4.0f*c.x);
  o.y = 0.3f*c.y - ((a.y + d.y + c.x + c.z) - 4.0f*c.y);
  o.z = 0.3f*c.z - ((a.z + d.z + c.y + c.w) - 4.0f*c.z);
  o.w = 0.3f*c.w - ((a.w + d.w + c.z + rt ) - 4.0f*c.w);
  return o;
}

__global__ __launch_bounds__(TPB, 4) void k_gmres(
    const float* __restrict__ b, const float* __restrict__ guess,
    float* __restrict__ x, float* __restrict__ wstag,
    float* __restrict__ pdA, float* __restrict__ pdB, float* __restrict__ pn,
    int* __restrict__ arrive)
{
  const int t = threadIdx.x, blk = blockIdx.x;
  const int elem = blk*(TPB*4) + t*4;
  const int i = elem >> 10, jc = elem & (NGRID-1);
  const int upo = ((i + NGRID-1) & (NGRID-1)) << 10;
  const int dno = ((i + 1) & (NGRID-1)) << 10;
  const int lfi = (i<<10) | ((jc + NGRID-1) & (NGRID-1));
  const int rti = (i<<10) | ((jc + 4) & (NGRID-1));
  const int lane = t & 63, wv = t >> 6;

  __shared__ float red[KMAX][16];
  __shared__ float sH[KMAX], hsave[KMAX];
  __shared__ float Hm[KMAX][RST];
  __shared__ float M[RST][RST+1];
  __shared__ float yv[RST];
  __shared__ float snrm, sBeta;

  float4 x4 = ld4(guess + elem);
  float4 w4;
  float4 vc[RST];
  int bid = 1;   // monotonically increasing barrier id

  #pragma unroll 1
  for (int cyc = 0; cyc < NCYC; ++cyc) {
    for (int q = t; q < KMAX*RST; q += TPB) ((float*)Hm)[q] = 0.0f;

    // ---- RESID: w = b - A(x); norm partial ----
    const float* xs = (cyc == 0) ? guess : x;
    float4 ax = stencil_scaled(xs, 1.0f, x4, upo, dno, lfi, rti, jc);
    float4 b4 = ld4(b + elem);
    w4.x = b4.x - ax.x; w4.y = b4.y - ax.y; w4.z = b4.z - ax.z; w4.w = b4.w - ax.w;
    st4(wstag + elem, w4);
    {
      float s = wave_reduce(dot4(w4, w4));
      if (lane == 0) red[16][wv] = s;
      __syncthreads();
      if (t == 0) {
        float acc = 0.f;
        #pragma unroll
        for (int q = 0; q < 16; ++q) acc += red[16][q];
        pn[blk] = acc;
      }
    }
    gridbar(arrive, bid++, blk, t, wv);

    #pragma unroll
    for (int J = 0; J < RST; ++J) {
      // ---- PHASE 1: norm -> inv; vc[J] = w*inv; w = A(wstag*inv); first dots ----
      {
        if (wv == 0) { float s = col_reduce256(pn, lane); if (lane == 0) snrm = s; }
        __syncthreads();
        float hn = sqrtf(snrm);
        float inv = 1.0f/(hn + 1e-12f);
        if (t == 0) { if (J == 0) sBeta = hn; else Hm[J][J-1] = hn; }
        vc[J].x = w4.x*inv; vc[J].y = w4.y*inv; vc[J].z = w4.z*inv; vc[J].w = w4.w*inv;
        w4 = stencil_scaled(wstag, inv, vc[J], upo, dno, lfi, rti, jc);
        #pragma unroll
        for (int k = 0; k <= J; ++k) {
          float s = wave_reduce(dot4(vc[k], w4));
          if (lane == 0) red[k][wv] = s;
        }
        __syncthreads();
        if (t <= J) {
          float acc = 0.f;
          #pragma unroll
          for (int q = 0; q < 16; ++q) acc += red[t][q];
          pdA[t*NB + blk] = acc;
        }
      }
      gridbar(arrive, bid++, blk, t, wv);
      // ---- PHASE 2: reduce h; axpy1; second dots ----
      {
        for (int k = wv; k <= J; k += 16) {
          float s = col_reduce256(pdA + k*NB, lane);
          if (lane == 0) sH[k] = s;
        }
        __syncthreads();
        #pragma unroll
        for (int k = 0; k <= J; ++k) {
          float hk = sH[k];
          w4.x -= hk*vc[k].x; w4.y -= hk*vc[k].y; w4.z -= hk*vc[k].z; w4.w -= hk*vc[k].w;
        }
        if (t <= J) hsave[t] = sH[t];
        #pragma unroll
        for (int k = 0; k <= J; ++k) {
          float s = wave_reduce(dot4(vc[k], w4));
          if (lane == 0) red[k][wv] = s;
        }
        __syncthreads();
        if (t <= J) {
          float acc = 0.f;
          #pragma unroll
          for (int q = 0; q < 16; ++q) acc += red[t][q];
          pdB[t*NB + blk] = acc;
        }
      }
      gridbar(arrive, bid++, blk, t, wv);
      // ---- PHASE 3: reduce h2; axpy2; Hm column; norm partial; stage w ----
      {
        for (int k = wv; k <= J; k += 16) {
          float s = col_reduce256(pdB + k*NB, lane);
          if (lane == 0) sH[k] = s;
        }
        __syncthreads();
        #pragma unroll
        for (int k = 0; k <= J; ++k) {
          float hk = sH[k];
          w4.x -= hk*vc[k].x; w4.y -= hk*vc[k].y; w4.z -= hk*vc[k].z; w4.w -= hk*vc[k].w;
        }
        if (t <= J) Hm[t][J] = hsave[t] + sH[t];
        float s = wave_reduce(dot4(w4, w4));
        if (lane == 0) red[16][wv] = s;
        __syncthreads();
        if (t == 0) {
          float acc = 0.f;
          #pragma unroll
          for (int q = 0; q < 16; ++q) acc += red[16][q];
          pn[blk] = acc;
        }
        if (J < RST-1) st4(wstag + elem, w4);
      }
      gridbar(arrive, bid++, blk, t, wv);
    }

    // ---- EPILOGUE: Hm[16][15]; solve 16x16 normal equations; x += V y ----
    {
      if (wv == 0) { float s = col_reduce256(pn, lane); if (lane == 0) snrm = s; }
      __syncthreads();
      if (t == 0) Hm[16][15] = sqrtf(snrm);
      __syncthreads();
      if (t < 256) {
        int a = t >> 4, bq = t & 15;
        float s = 0.f;
        #pragma unroll
        for (int k = 0; k < KMAX; ++k) s += Hm[k][a]*Hm[k][bq];
        M[a][bq] = s + (a == bq ? 1e-12f : 0.0f);
      }
      __syncthreads();
      if (t < RST) M[t][RST] = sBeta * Hm[0][t];
      __syncthreads();
      for (int c = 0; c < RST; ++c) {
        if (t == 0) {
          int p = c; float mx = fabsf(M[c][c]);
          for (int r = c+1; r < RST; ++r){ float v=fabsf(M[r][c]); if (v>mx){mx=v;p=r;} }
          if (p != c) for (int cc = c; cc <= RST; ++cc){ float tmp=M[c][cc]; M[c][cc]=M[p][cc]; M[p][cc]=tmp; }
        }
        __syncthreads();
        if (t > c && t < RST) {
          float f = M[t][c]/M[c][c];
          for (int cc = c; cc <= RST; ++cc) M[t][cc] -= f*M[c][cc];
        }
        __syncthreads();
      }
      if (t == 0) {
        for (int c = RST-1; c >= 0; --c) {
          float s = M[c][RST];
          for (int cc = c+1; cc < RST; ++cc) s -= M[c][cc]*yv[cc];
          yv[c] = s/M[c][c];
        }
      }
      __syncthreads();
      #pragma unroll
      for (int k = 0; k < RST; ++k) {
        float yk = yv[k];
        x4.x += yk*vc[k].x; x4.y += yk*vc[k].y; x4.z += yk*vc[k].z; x4.w += yk*vc[k].w;
      }
      st4(x + elem, x4);
    }
    if (cyc < NCYC-1)
      gridbar(arrive, bid++, blk, t, wv);   // x visible for next cycle's residual
  }
}

extern "C" void kernel_launch(void* const* d_in, const int* in_sizes, int n_in,
                              void* d_out, int out_size, void* d_ws, size_t ws_size,
                              hipStream_t stream) {
  const float* b     = (const float*)d_in[0];   // source
  const float* guess = (const float*)d_in[1];   // initial guess
  float* x  = (float*)d_out;
  float* ws = (float*)d_ws;

  float* wstag = ws;                       // NE
  float* pdA   = ws + NE;                  // KMAX*NB
  float* pdB   = pdA + KMAX*NB;            // KMAX*NB
  float* pn    = pdB + KMAX*NB;            // NB
  int*   barm  = (int*)(pn + NB);          // arrive[NB*FLAG_STRIDE]

  hipMemsetAsync(barm, 0, NB*FLAG_STRIDE*sizeof(int), stream);

  k_gmres<<<NB, TPB, 0, stream>>>(b, guess, x, wstag, pdA, pdB, pn, barm);
}

// Round 6
// 1328.073 us; speedup vs baseline: 5.5232x; 2.3234x over previous
//
#include <hip/hip_runtime.h>
#include <math.h>

// Restarted GMRES(16), 4 cycles, Helmholtz (-lap + 0.3) on 1024x1024 periodic fp32.
// Round 6: persistent kernel, register-resident basis vc[16]; LDS tile for w/x rows
// (only 2 boundary rows/block go through global); fenceless barrier protocol using
// relaxed agent-scope atomics (no buffer_inv/wbl2 per phase); Gram-matrix CGS2
// (h2 = h1 - G h1, norm via formula) -> 2 barriers/step, 131 barriers total.

#define NGRID 1024
#define NE (NGRID*NGRID)
#define NB 256            // blocks = CUs; one 16-wave block per CU
#define TPB 1024
#define RST 16
#define KMAX 17
#define NCYC 4
#define FLAG_STRIDE 16    // pad flags to 64B

__device__ __forceinline__ float4 ld4(const float* p){return *reinterpret_cast<const float4*>(p);}
__device__ __forceinline__ void st4(float* p, float4 v){*reinterpret_cast<float4*>(p)=v;}
__device__ __forceinline__ float dot4(float4 a,float4 b){return a.x*b.x+a.y*b.y+a.z*b.z+a.w*b.w;}

// coherent (IC-level) scalar accesses: relaxed agent-scope atomics.
__device__ __forceinline__ float ldc(const float* p){
  return __hip_atomic_load(p, __ATOMIC_RELAXED, __HIP_MEMORY_SCOPE_AGENT);
}
__device__ __forceinline__ void stc(float* p, float v){
  __hip_atomic_store(p, v, __ATOMIC_RELAXED, __HIP_MEMORY_SCOPE_AGENT);
}
__device__ __forceinline__ float4 ldc4(const float* p){
  float4 r; r.x=ldc(p); r.y=ldc(p+1); r.z=ldc(p+2); r.w=ldc(p+3); return r;
}
__device__ __forceinline__ void stc4(float* p, float4 v){
  stc((float*)p+0,v.x); stc((float*)p+1,v.y); stc((float*)p+2,v.z); stc((float*)p+3,v.w);
}
__device__ __forceinline__ int ldci(const int* p){
  return __hip_atomic_load(p, __ATOMIC_RELAXED, __HIP_MEMORY_SCOPE_AGENT);
}
__device__ __forceinline__ void stci(int* p, int v){
  __hip_atomic_store(p, v, __ATOMIC_RELAXED, __HIP_MEMORY_SCOPE_AGENT);
}

__device__ __forceinline__ float wave_reduce(float s){
  #pragma unroll
  for(int off=32; off; off>>=1) s += __shfl_down(s,off);
  return s;
}

// fenceless tree barrier: blocks release (via syncthreads' vmcnt drain) their
// arrive flag; block 0 scans all flags (64 lanes x 4), then broadcasts gen;
// other blocks poll gen. All data crossing blocks uses ldc/stc (IC-coherent),
// so no cache invalidate/writeback is needed.
__device__ __forceinline__ void gridbar(int* arrive, int* gen, int bar_id,
                                        int blk, int t){
  __syncthreads();   // compiler emits s_waitcnt vmcnt(0) per wave -> stores acked
  if (blk == 0) {
    if (t < 64) {
      if (t == 0) stci(&arrive[0], bar_id);
      #pragma unroll
      for (int q = 0; q < NB/64; ++q) {
        while (ldci(&arrive[(t + q*64)*FLAG_STRIDE]) < bar_id)
          __builtin_amdgcn_s_sleep(2);
      }
    }
    __syncthreads();
    if (t == 0) stci(gen, bar_id);
  } else {
    if (t == 0) {
      stci(&arrive[blk*FLAG_STRIDE], bar_id);
      while (ldci(gen) < bar_id) __builtin_amdgcn_s_sleep(2);
    }
    __syncthreads();
  }
}

// stencil over LDS tile (own 4 rows) + coherent global boundary rows.
// center c already scaled by inv; neighbors unscaled -> *inv.
__device__ __forceinline__ float4 stencil_t(const float (*wt)[NGRID],
                                            const float* gup, const float* gdn,
                                            float4 c, float inv, int lr, int cq){
  float4 a = (lr==0) ? ldc4(gup + cq) : ld4(&wt[lr-1][cq]);
  float4 d = (lr==3) ? ldc4(gdn + cq) : ld4(&wt[lr+1][cq]);
  float lf = wt[lr][(cq+NGRID-1)&(NGRID-1)] * inv;
  float rt = wt[lr][(cq+4)&(NGRID-1)]       * inv;
  a.x*=inv; a.y*=inv; a.z*=inv; a.w*=inv;
  d.x*=inv; d.y*=inv; d.z*=inv; d.w*=inv;
  float4 o;
  o.x = 0.3f*c.x - ((a.x + d.x + lf  + c.y) - 4.0f*c.x);
  o.y = 0.3f*c.y - ((a.y + d.y + c.x + c.z) - 4.0f*c.y);
  o.z = 0.3f*c.z - ((a.z + d.z + c.y + c.w) - 4.0f*c.z);
  o.w = 0.3f*c.w - ((a.w + d.w + c.z + rt ) - 4.0f*c.w);
  return o;
}

// plain global stencil (cycle-0 residual on pristine `guess`)
__device__ __forceinline__ float4 stencil_g(const float* __restrict__ u,
                                            float4 c, int gi, int cq){
  const float* up = u + (((gi+NGRID-1)&(NGRID-1))<<10);
  const float* dn = u + (((gi+1)&(NGRID-1))<<10);
  float4 a = ld4(up+cq), d = ld4(dn+cq);
  float lf = u[(gi<<10)|((cq+NGRID-1)&(NGRID-1))];
  float rt = u[(gi<<10)|((cq+4)&(NGRID-1))];
  float4 o;
  o.x = 0.3f*c.x - ((a.x + d.x + lf  + c.y) - 4.0f*c.x);
  o.y = 0.3f*c.y - ((a.y + d.y + c.x + c.z) - 4.0f*c.y);
  o.z = 0.3f*c.z - ((a.z + d.z + c.y + c.w) - 4.0f*c.z);
  o.w = 0.3f*c.w - ((a.w + d.w + c.z + rt ) - 4.0f*c.w);
  return o;
}

__global__ __launch_bounds__(TPB, 4) void k_gmres(
    const float* __restrict__ b, const float* __restrict__ guess,
    float* __restrict__ x, float* __restrict__ wstag,
    float* __restrict__ pdA, float* __restrict__ pn,
    int* __restrict__ arrive, int* __restrict__ gen)
{
  const int t = threadIdx.x, blk = blockIdx.x;
  const int lr = t >> 8;                 // local row 0..3
  const int cq = (t & 255) << 2;         // col of this thread's 4 elems
  const int gi = blk*4 + lr;             // global row
  const int gelem = (gi<<10) + cq;
  const int lane = t & 63, wv = t >> 6;
  const float* wup = wstag + (((gi+NGRID-1)&(NGRID-1))<<10);
  const float* wdn = wstag + (((gi+1)&(NGRID-1))<<10);
  const float* xup = x + (((gi+NGRID-1)&(NGRID-1))<<10);
  const float* xdn = x + (((gi+1)&(NGRID-1))<<10);

  __shared__ float wt[4][NGRID];         // 16 KB staging tile (w3 / x)
  __shared__ float red[KMAX][16];
  __shared__ float sH[KMAX];             // h1 ([16] = ||w||^2)
  __shared__ float sC[KMAX];             // c = h1 + h2
  __shared__ float G[KMAX][KMAX];        // Gram matrix V^T V
  __shared__ float Hm[KMAX][RST];
  __shared__ float M[RST][RST+1];
  __shared__ float yv[RST];
  __shared__ float sBeta, sInv;

  float4 x4 = ld4(guess + gelem);
  float4 w4;
  float4 vcr[RST];
  int bid = 1;

  #pragma unroll 1
  for (int cyc = 0; cyc < NCYC; ++cyc) {
    for (int q = t; q < KMAX*KMAX; q += TPB) ((float*)G)[q] = 0.0f;
    for (int q = t; q < KMAX*RST; q += TPB) ((float*)Hm)[q] = 0.0f;
    if (t == 0) G[0][0] = 1.0f;

    // ---- RESID: w = b - A(x) ----
    float4 ax = (cyc == 0) ? stencil_g(guess, x4, gi, cq)
                           : stencil_t(wt, xup, xdn, x4, 1.0f, lr, cq);
    float4 b4 = ld4(b + gelem);
    w4.x = b4.x - ax.x; w4.y = b4.y - ax.y; w4.z = b4.z - ax.z; w4.w = b4.w - ax.w;
    __syncthreads();                      // wt (x) reads done before overwrite
    st4(&wt[lr][cq], w4);
    if (lr == 0 || lr == 3) stc4(wstag + gelem, w4);   // boundary rows only
    {
      float s = wave_reduce(dot4(w4, w4));
      if (lane == 0) red[16][wv] = s;
      __syncthreads();
      if (t == 0) {
        float acc = 0.f;
        #pragma unroll
        for (int q = 0; q < 16; ++q) acc += red[16][q];
        stc(&pn[blk], acc);
      }
    }
    gridbar(arrive, gen, bid++, blk, t);

    #pragma unroll
    for (int J = 0; J < RST; ++J) {
      // ---- P1: v_J = w*inv; w = A(v_J); dots h1 (+||w||^2) ----
      if (J == 0) {
        if (wv == 0) {
          int ba = lane*4;
          float s2 = ldc(&pn[ba]) + ldc(&pn[ba+1]) + ldc(&pn[ba+2]) + ldc(&pn[ba+3]);
          s2 = wave_reduce(s2);
          if (lane == 0) { float beta = sqrtf(s2); sBeta = beta; sInv = 1.0f/(beta + 1e-12f); }
        }
        __syncthreads();
      }
      {
        float inv = sInv;
        vcr[J].x = w4.x*inv; vcr[J].y = w4.y*inv; vcr[J].z = w4.z*inv; vcr[J].w = w4.w*inv;
        w4 = stencil_t(wt, wup, wdn, vcr[J], inv, lr, cq);
        #pragma unroll
        for (int k = 0; k <= J; ++k) {
          float s = wave_reduce(dot4(vcr[k], w4));
          if (lane == 0) red[k][wv] = s;
        }
        {
          float s = wave_reduce(dot4(w4, w4));
          if (lane == 0) red[16][wv] = s;
        }
        __syncthreads();
        if (t <= J) {
          float acc = 0.f;
          #pragma unroll
          for (int q = 0; q < 16; ++q) acc += red[t][q];
          stc(&pdA[t*NB + blk], acc);
        }
        if (t == 16) {
          float acc = 0.f;
          #pragma unroll
          for (int q = 0; q < 16; ++q) acc += red[16][q];
          stc(&pdA[16*NB + blk], acc);
        }
      }
      gridbar(arrive, gen, bid++, blk, t);

      // ---- P2: reduce h1; Gram-CGS2 tiny math; axpy; stage w3 ----
      {
        for (int kk = wv; kk <= J+1; kk += 16) {
          int col = (kk <= J) ? kk : 16;
          int base = col*NB + lane*4;
          float s2 = ldc(&pdA[base]) + ldc(&pdA[base+1]) + ldc(&pdA[base+2]) + ldc(&pdA[base+3]);
          s2 = wave_reduce(s2);
          if (lane == 0) sH[col] = s2;
        }
        __syncthreads();
        if (t < 64) {   // c = 2 h1 - G h1
          int k = t;
          double h1k = (k <= J) ? (double)sH[k] : 0.0;
          double g1k = 0.0;
          for (int m = 0; m <= J; ++m) g1k += (double)G[k][m]*(double)sH[m];
          double ck = 2.0*h1k - g1k;
          if (k <= J) sC[k] = (float)ck;
        }
        __syncthreads();
        if (t < 64) {   // hn^2 = ||w||^2 - 2 c.h1 + c^T G c ; update G, Hm
          int k = t;
          double h1k = (k <= J) ? (double)sH[k] : 0.0;
          double ck  = (k <= J) ? (double)sC[k] : 0.0;
          double gck = 0.0;
          for (int m = 0; m <= J; ++m) gck += (double)G[k][m]*(double)sC[m];
          double part = ck*(gck - 2.0*h1k);
          #pragma unroll
          for (int off = 32; off; off >>= 1) part += __shfl_xor(part, off);
          double hn2 = (double)sH[16] + part;
          double hn = sqrt(hn2 > 0.0 ? hn2 : 0.0);
          if (k == 0) { sInv = (float)(1.0/(hn + 1e-12)); Hm[J+1][J] = (float)hn; }
          if (k <= J) Hm[k][J] = sC[k];
          if (J < RST-1) {
            if (k <= J) { float gn = (float)((h1k - gck)/hn); G[k][J+1] = gn; G[J+1][k] = gn; }
            if (k == 0) G[J+1][J+1] = 1.0f;
          }
        }
        __syncthreads();
        if (J < RST-1) {
          #pragma unroll
          for (int k = 0; k <= J; ++k) {
            float hk = sC[k];
            w4.x -= hk*vcr[k].x; w4.y -= hk*vcr[k].y; w4.z -= hk*vcr[k].z; w4.w -= hk*vcr[k].w;
          }
          st4(&wt[lr][cq], w4);
          if (lr == 0 || lr == 3) stc4(wstag + gelem, w4);
          gridbar(arrive, gen, bid++, blk, t);
        }
      }
    }

    // ---- EPILOGUE (all-local): solve 16x16 normal equations; x += V y ----
    {
      if (t < 256) {
        int a = t >> 4, bq = t & 15;
        float s = 0.f;
        #pragma unroll
        for (int k = 0; k < KMAX; ++k) s += Hm[k][a]*Hm[k][bq];
        M[a][bq] = s + (a == bq ? 1e-12f : 0.0f);
      }
      __syncthreads();
      if (t < RST) M[t][RST] = sBeta * Hm[0][t];
      __syncthreads();
      for (int c = 0; c < RST; ++c) {
        if (t == 0) {
          int p = c; float mx = fabsf(M[c][c]);
          for (int r = c+1; r < RST; ++r){ float v=fabsf(M[r][c]); if (v>mx){mx=v;p=r;} }
          if (p != c) for (int cc = c; cc <= RST; ++cc){ float tmp=M[c][cc]; M[c][cc]=M[p][cc]; M[p][cc]=tmp; }
        }
        __syncthreads();
        if (t > c && t < RST) {
          float f = M[t][c]/M[c][c];
          for (int cc = c; cc <= RST; ++cc) M[t][cc] -= f*M[c][cc];
        }
        __syncthreads();
      }
      if (t == 0) {
        for (int c = RST-1; c >= 0; --c) {
          float s = M[c][RST];
          for (int cc = c+1; cc < RST; ++cc) s -= M[c][cc]*yv[cc];
          yv[c] = s/M[c][c];
        }
      }
      __syncthreads();
      #pragma unroll
      for (int k = 0; k < RST; ++k) {
        float yk = yv[k];
        x4.x += yk*vcr[k].x; x4.y += yk*vcr[k].y; x4.z += yk*vcr[k].z; x4.w += yk*vcr[k].w;
      }
      __syncthreads();                 // wt free (last read was P1@15)
      st4(&wt[lr][cq], x4);            // stage x for next cycle's residual stencil
      if (lr == 0 || lr == 3) stc4(x + gelem, x4);
      else                    st4(x + gelem, x4);
    }
    if (cyc < NCYC-1) gridbar(arrive, gen, bid++, blk, t);
  }
}

extern "C" void kernel_launch(void* const* d_in, const int* in_sizes, int n_in,
                              void* d_out, int out_size, void* d_ws, size_t ws_size,
                              hipStream_t stream) {
  const float* b     = (const float*)d_in[0];   // source
  const float* guess = (const float*)d_in[1];   // initial guess
  float* x  = (float*)d_out;
  float* ws = (float*)d_ws;

  float* wstag = ws;                       // NE (only boundary rows used)
  float* pdA   = ws + NE;                  // KMAX*NB
  float* pn    = pdA + KMAX*NB;            // NB
  int*   barm  = (int*)(pn + NB);          // arrive[NB*FS] + gen

  hipMemsetAsync(barm, 0, (NB+1)*FLAG_STRIDE*sizeof(int), stream);

  k_gmres<<<NB, TPB, 0, stream>>>(b, guess, x, wstag, pdA, pn,
                                  barm, barm + NB*FLAG_STRIDE);
}